// Round 21
// baseline (5903.325 us; speedup 1.0000x reference)
//
#include <hip/hip_runtime.h>
#include <hip/hip_bf16.h>
#include <stdint.h>

#define DD   1024
#define TD   3072
#define DFFN 4096
#define NL   12
#define SS   1040
#define SP   1056          /* padded seq for attention operand arena */
#define BB   8
#define MM   (BB*SS)       /* 8320 */
#define HH   16
#define NTAIL 32           /* leading tail blocks in attn_staged grid (4 waves each) */

typedef float  f32x4  __attribute__((ext_vector_type(4)));
typedef __bf16 bf16x8 __attribute__((ext_vector_type(8)));
typedef unsigned short u16;

union Bf8 { bf16x8 v; u16 s[8]; };

__device__ __forceinline__ u16 f2b(float f) {
  union { float f; unsigned u; } x; x.f = f;
  unsigned r = (x.u + 0x7FFFu + ((x.u >> 16) & 1u)) >> 16;
  return (u16)r;
}

__device__ __forceinline__ f32x4 mfma_bf16(bf16x8 a, bf16x8 b, f32x4 c) {
  return __builtin_amdgcn_mfma_f32_16x16x32_bf16(a, b, c, 0, 0, 0);
}

__device__ __forceinline__ void gload_lds16(const u16* g, u16* l) {
  __builtin_amdgcn_global_load_lds((const __attribute__((address_space(1))) void*)g,
                                   (__attribute__((address_space(3))) void*)l, 16, 0, 0);
}

// 16-lane max reduce via DPP (quad_perm xor1, xor2, row_ror:4, row_ror:8) — VALU-speed.
__device__ __forceinline__ float dppmax16(float t) {
  union { float f; int i; } u, v;
  u.f = t;
  v.i = __builtin_amdgcn_update_dpp(0, u.i, 0xB1, 0xF, 0xF, true);   // quad_perm [1,0,3,2]
  u.f = fmaxf(u.f, v.f);
  v.i = __builtin_amdgcn_update_dpp(0, u.i, 0x4E, 0xF, 0xF, true);   // quad_perm [2,3,0,1]
  u.f = fmaxf(u.f, v.f);
  v.i = __builtin_amdgcn_update_dpp(0, u.i, 0x124, 0xF, 0xF, true);  // row_ror:4
  u.f = fmaxf(u.f, v.f);
  v.i = __builtin_amdgcn_update_dpp(0, u.i, 0x128, 0xF, 0xF, true);  // row_ror:8
  u.f = fmaxf(u.f, v.f);
  return u.f;
}

// ---------------- weight cast+transpose: in (K,N) f32 -> out (N,K) bf16, per layer z ----
__global__ __launch_bounds__(256)
void transpose_cast(const float* __restrict__ in, u16* __restrict__ out, int K, int N) {
  __shared__ float tile[32][33];
  const int n0 = blockIdx.x * 32, k0 = blockIdx.y * 32;
  const size_t lb = (size_t)blockIdx.z * K * N;
  const int tx = threadIdx.x, ty = threadIdx.y;
  for (int j = 0; j < 4; ++j)
    tile[ty + 8*j][tx] = in[lb + (size_t)(k0 + ty + 8*j) * N + n0 + tx];
  __syncthreads();
  for (int j = 0; j < 4; ++j)
    out[lb + (size_t)(n0 + ty + 8*j) * K + k0 + tx] = f2b(tile[tx][ty + 8*j]);
}

// ---------------- LayerNorm: row of 1024 -> bf16 out --------------------------------
__global__ __launch_bounds__(256)
void ln_kernel(const float* __restrict__ in, const float* __restrict__ gam,
               const float* __restrict__ bet, u16* __restrict__ outb) {
  const int row = blockIdx.x, t = threadIdx.x;
  const float4 v = ((const float4*)(in + (size_t)row * DD))[t];
  float s  = v.x + v.y + v.z + v.w;
  float s2 = v.x*v.x + v.y*v.y + v.z*v.z + v.w*v.w;
  for (int off = 1; off < 64; off <<= 1) { s += __shfl_xor(s, off); s2 += __shfl_xor(s2, off); }
  __shared__ float red[8];
  if ((t & 63) == 0) { red[t >> 6] = s; red[4 + (t >> 6)] = s2; }
  __syncthreads();
  s  = red[0] + red[1] + red[2] + red[3];
  s2 = red[4] + red[5] + red[6] + red[7];
  const float mu = s * (1.0f/1024.0f);
  const float var = s2 * (1.0f/1024.0f) - mu*mu;
  const float rs = rsqrtf(var + 1e-6f);
  const float4 gv = ((const float4*)gam)[t];
  const float4 bv = ((const float4*)bet)[t];
  ushort4 o;
  o.x = f2b((v.x - mu)*rs*gv.x + bv.x);
  o.y = f2b((v.y - mu)*rs*gv.y + bv.y);
  o.z = f2b((v.z - mu)*rs*gv.z + bv.z);
  o.w = f2b((v.w - mu)*rs*gv.w + bv.w);
  ((ushort4*)(outb + (size_t)row * DD))[t] = o;
}

// ---------------- LN with split-K combine: x = P0 + P1; writes h (resid) + LN out -----
// OUTF=0: bf16 LN out.  OUTF=1: f32 LN out (final).
template<int OUTF>
__global__ __launch_bounds__(256)
void ln_comb(const float* __restrict__ P0, const float* __restrict__ P1,
             float* __restrict__ hout, const float* __restrict__ gam,
             const float* __restrict__ bet, u16* __restrict__ outb,
             float* __restrict__ outf) {
  const int row = blockIdx.x, t = threadIdx.x;
  const float4 a = ((const float4*)(P0 + (size_t)row * DD))[t];
  const float4 b = ((const float4*)(P1 + (size_t)row * DD))[t];
  float4 v; v.x = a.x + b.x; v.y = a.y + b.y; v.z = a.z + b.z; v.w = a.w + b.w;
  ((float4*)(hout + (size_t)row * DD))[t] = v;
  float s  = v.x + v.y + v.z + v.w;
  float s2 = v.x*v.x + v.y*v.y + v.z*v.z + v.w*v.w;
  for (int off = 1; off < 64; off <<= 1) { s += __shfl_xor(s, off); s2 += __shfl_xor(s2, off); }
  __shared__ float red[8];
  if ((t & 63) == 0) { red[t >> 6] = s; red[4 + (t >> 6)] = s2; }
  __syncthreads();
  s  = red[0] + red[1] + red[2] + red[3];
  s2 = red[4] + red[5] + red[6] + red[7];
  const float mu = s * (1.0f/1024.0f);
  const float var = s2 * (1.0f/1024.0f) - mu*mu;
  const float rs = rsqrtf(var + 1e-6f);
  const float4 gv = ((const float4*)gam)[t];
  const float4 bv = ((const float4*)bet)[t];
  const float y0 = (v.x - mu)*rs*gv.x + bv.x;
  const float y1 = (v.y - mu)*rs*gv.y + bv.y;
  const float y2 = (v.z - mu)*rs*gv.z + bv.z;
  const float y3 = (v.w - mu)*rs*gv.w + bv.w;
  if (OUTF) {
    float4 o; o.x=y0; o.y=y1; o.z=y2; o.w=y3;
    ((float4*)(outf + (size_t)row * DD))[t] = o;
  } else {
    ushort4 o; o.x=f2b(y0); o.y=f2b(y1); o.z=f2b(y2); o.w=f2b(y3);
    ((ushort4*)(outb + (size_t)row * DD))[t] = o;
  }
}

// ---------------- 128² GEMM: C(M,N) = A(M,K)bf16 @ Bt(N,K)bf16^T + bias [+ epi] --------
// EPI 1: gelu, write bf16.  EPI 3: qkv scatter.
// nb-fastest decode: consecutive (same-XCD) blocks share the A-panel. 4 blocks/CU.
template<int EPI>
__global__ __launch_bounds__(256, 4)
void gemm_bt(const u16* __restrict__ A, const u16* __restrict__ Bt,
             const float* __restrict__ bias,
             u16* outB,
             u16* __restrict__ qb, u16* __restrict__ kb, u16* __restrict__ vtb,
             int N, int K) {
  __shared__ u16 As[128*64];
  __shared__ u16 Bs[128*64];
  const int tid = threadIdx.x;

  const int nwg = gridDim.x * gridDim.y;
  int wgid = blockIdx.y * gridDim.x + blockIdx.x;
  wgid = (wgid & 7) * (nwg >> 3) + (wgid >> 3);
  const int nb = wgid % gridDim.y;
  const int mb = wgid / gridDim.y;
  const int m0 = mb * 128, n0 = nb * 128;

  const int lane = tid & 63, w = tid >> 6;
  const int wr = (w >> 1) * 64, wc = (w & 1) * 64;
  const int c = lane & 15, g = lane >> 4;

  f32x4 acc[4][4];
  for (int i = 0; i < 4; ++i) for (int j = 0; j < 4; ++j) acc[i][j] = f32x4{0.f,0.f,0.f,0.f};

  const int srow = tid >> 3, scg = tid & 7;
  const size_t aoff = (size_t)(m0 + srow) * K + scg * 8;
  const size_t boff = (size_t)(n0 + srow) * K + scg * 8;

  for (int kt = 0; kt < K; kt += 64) {
    for (int it = 0; it < 4; ++it) {
      gload_lds16(A  + aoff + (size_t)it * 32 * K + kt, As + (it*256 + tid) * 8);
      gload_lds16(Bt + boff + (size_t)it * 32 * K + kt, Bs + (it*256 + tid) * 8);
    }
    __syncthreads();
    for (int kk = 0; kk < 2; ++kk) {
      bf16x8 af[4], bfr[4];
      for (int i = 0; i < 4; ++i) af[i]  = *(const bf16x8*)(As + (wr + i*16 + c)*64 + kk*32 + g*8);
      for (int j = 0; j < 4; ++j) bfr[j] = *(const bf16x8*)(Bs + (wc + j*16 + c)*64 + kk*32 + g*8);
      for (int i = 0; i < 4; ++i)
        for (int j = 0; j < 4; ++j)
          acc[i][j] = mfma_bf16(af[i], bfr[j], acc[i][j]);
    }
    __syncthreads();
  }

  for (int j = 0; j < 4; ++j) {
    const int col = n0 + wc + j*16 + c;
    const float bcol = bias[col];
    for (int i = 0; i < 4; ++i) {
      const int row0 = m0 + wr + i*16 + 4*g;
      if (EPI == 3) {
        const int part = col >> 10;
        const int hh2  = (col >> 6) & 15;
        const int hd   = col & 63;
        const int bb   = (int)((unsigned)row0 / SS);
        const int s0   = row0 - bb * SS;          // 4-aligned; never crosses batch
        const size_t bh = (size_t)(bb * HH + hh2);
        if (part == 2) {
          ushort4 pk;
          pk.x = f2b(acc[i][j][0] + bcol);
          pk.y = f2b(acc[i][j][1] + bcol);
          pk.z = f2b(acc[i][j][2] + bcol);
          pk.w = f2b(acc[i][j][3] + bcol);
          *(ushort4*)(vtb + (bh*64 + hd)*SP + s0) = pk;
        } else if (part == 0) {
          for (int r = 0; r < 4; ++r)
            qb[(bh*SP + s0 + r)*64 + hd] = f2b((acc[i][j][r] + bcol) * 0.125f);
        } else {
          for (int r = 0; r < 4; ++r)
            kb[(bh*SP + s0 + r)*64 + hd] = f2b(acc[i][j][r] + bcol);
        }
      } else {
        for (int r = 0; r < 4; ++r) {
          const size_t idx = (size_t)(row0 + r) * N + col;
          const float v = acc[i][j][r] + bcol;
          const float z = 1.5957691216f * (v + 0.044715f * v * v * v);
          const float e = __expf(z);
          outB[idx] = f2b(v * e * __builtin_amdgcn_rcpf(e + 1.0f));
        }
      }
    }
  }
}

// ---------------- split-K 128² GEMM (blockIdx.z = K-half), for WO and FFN2 ------------
// kh=0 writes P0 = acc(K-half 0) + bias + resid; kh=1 writes P1 = acc(K-half 1).
// Combine happens in the following ln_comb. Grid 65 x 8 x 2 = 1040 blocks (4.06/CU).
__global__ __launch_bounds__(256, 4)
void gemm_splitk(const u16* __restrict__ A, const u16* __restrict__ Bt,
                 const float* __restrict__ bias, const float* __restrict__ resid,
                 float* __restrict__ P0, float* __restrict__ P1, int N, int K) {
  __shared__ u16 As[128*64];
  __shared__ u16 Bs[128*64];
  const int tid = threadIdx.x;
  const int kh = blockIdx.z;

  const int nwg = gridDim.x * gridDim.y;
  int wgid = blockIdx.y * gridDim.x + blockIdx.x;
  wgid = (wgid & 7) * (nwg >> 3) + (wgid >> 3);
  const int nb = wgid % gridDim.y;
  const int mb = wgid / gridDim.y;
  const int m0 = mb * 128, n0 = nb * 128;

  const int lane = tid & 63, w = tid >> 6;
  const int wr = (w >> 1) * 64, wc = (w & 1) * 64;
  const int c = lane & 15, g = lane >> 4;

  f32x4 acc[4][4];
  for (int i = 0; i < 4; ++i) for (int j = 0; j < 4; ++j) acc[i][j] = f32x4{0.f,0.f,0.f,0.f};

  const int KH = K >> 1;
  const int srow = tid >> 3, scg = tid & 7;
  const size_t aoff = (size_t)(m0 + srow) * K + scg * 8 + (size_t)kh * KH;
  const size_t boff = (size_t)(n0 + srow) * K + scg * 8 + (size_t)kh * KH;

  for (int kt = 0; kt < KH; kt += 64) {
    for (int it = 0; it < 4; ++it) {
      gload_lds16(A  + aoff + (size_t)it * 32 * K + kt, As + (it*256 + tid) * 8);
      gload_lds16(Bt + boff + (size_t)it * 32 * K + kt, Bs + (it*256 + tid) * 8);
    }
    __syncthreads();
    for (int kk = 0; kk < 2; ++kk) {
      bf16x8 af[4], bfr[4];
      for (int i = 0; i < 4; ++i) af[i]  = *(const bf16x8*)(As + (wr + i*16 + c)*64 + kk*32 + g*8);
      for (int j = 0; j < 4; ++j) bfr[j] = *(const bf16x8*)(Bs + (wc + j*16 + c)*64 + kk*32 + g*8);
      for (int i = 0; i < 4; ++i)
        for (int j = 0; j < 4; ++j)
          acc[i][j] = mfma_bf16(af[i], bfr[j], acc[i][j]);
    }
    __syncthreads();
  }

  float* outP = kh ? P1 : P0;
  for (int j = 0; j < 4; ++j) {
    const int col = n0 + wc + j*16 + c;
    const float bcol = kh ? 0.f : bias[col];
    for (int i = 0; i < 4; ++i) {
      const int row0 = m0 + wr + i*16 + 4*g;
      for (int r = 0; r < 4; ++r) {
        const size_t idx = (size_t)(row0 + r) * N + col;
        float v = acc[i][j][r] + bcol;
        if (!kh) v += resid[idx];
        outP[idx] = v;
      }
    }
  }
}

// ---------------- staged attention + fused tail; 256-thr blocks, 2 q-tiles/wave -------
// Staged path adds defer-max (THR=8): skip the o-rescale when per-tile max growth <= 8.
__global__ __launch_bounds__(256, 4)
void attn_staged(const u16* __restrict__ Qb, const u16* __restrict__ Kb,
                 const u16* __restrict__ VTb, u16* __restrict__ out,
                 const int* __restrict__ npt) {
  __shared__ u16 KV[2][4096];       // per buf: [0..2048) K tile, [2048..4096) V tile
  __shared__ u16 PT[4][640];        // per-wave P^T, 16 rows x 40 u16 (bf16)
  const int tid = threadIdx.x;
  const int w = tid >> 6, lane = tid & 63;
  const int c = lane & 15, g = lane >> 4;
  const int nin = npt[0];
  u16* pw = PT[w];

  if (blockIdx.x < NTAIL) {
    const int bh = blockIdx.x * 4 + w;
    const int b = bh >> 4, hh = bh & 15;
    const int q0 = 64 * 16;

    bf16x8 aq0, aq1;
    {
      const u16* qp = Qb + ((size_t)bh * SP + q0 + c) * 64 + g * 8;
      aq0 = *(const bf16x8*)qp;
      aq1 = *(const bf16x8*)(qp + 32);
    }

    float m[4], ls[4];
    f32x4 o[4];
    int qrow[4];
    for (int r = 0; r < 4; ++r) { m[r] = -1e30f; ls[r] = 0.f; qrow[r] = q0 + 4*g + r; }
    for (int nd = 0; nd < 4; ++nd) o[nd] = f32x4{0.f,0.f,0.f,0.f};

    for (int kt = 0; kt < 33; ++kt) {
      const int k0 = kt * 32;

      f32x4 s[2];
      {
        const u16* kp0 = Kb + ((size_t)bh * SP + k0 + c) * 64 + g * 8;
        f32x4 z0 = f32x4{0.f,0.f,0.f,0.f};
        z0 = mfma_bf16(aq0, *(const bf16x8*)kp0, z0);
        z0 = mfma_bf16(aq1, *(const bf16x8*)(kp0 + 32), z0);
        s[0] = z0;
        const u16* kp1 = kp0 + 16 * 64;
        f32x4 z1 = f32x4{0.f,0.f,0.f,0.f};
        z1 = mfma_bf16(aq0, *(const bf16x8*)kp1, z1);
        z1 = mfma_bf16(aq1, *(const bf16x8*)(kp1 + 32), z1);
        s[1] = z1;
      }

      for (int jt = 0; jt < 2; ++jt) {
        const int j = k0 + jt*16 + c;
        for (int r = 0; r < 4; ++r) {
          const int q = qrow[r];
          const bool blocked = (j >= SS) || ((q >= nin) && (j >= nin) && (j > q));
          if (blocked) s[jt][r] = -1e30f;
        }
      }

      for (int r = 0; r < 4; ++r) {
        float t = fmaxf(s[0][r], s[1][r]);
        for (int off = 1; off < 16; off <<= 1) t = fmaxf(t, __shfl_xor(t, off));
        const float mn = fmaxf(m[r], t);
        const float al = __expf(m[r] - mn);
        m[r] = mn;
        const float p0 = __expf(s[0][r] - mn);
        const float p1 = __expf(s[1][r] - mn);
        s[0][r] = p0; s[1][r] = p1;
        float ps = p0 + p1;
        for (int off = 1; off < 16; off <<= 1) ps += __shfl_xor(ps, off);
        ls[r] = ls[r] * al + ps;
        for (int nd = 0; nd < 4; ++nd) o[nd][r] *= al;
      }

      for (int jt = 0; jt < 2; ++jt)
        for (int r = 0; r < 4; ++r)
          pw[(4*g + r)*40 + jt*16 + c] = f2b(s[jt][r]);
      __builtin_amdgcn_sched_barrier(0);
      bf16x8 ap = *(const bf16x8*)(pw + c*40 + 8*g);
      __builtin_amdgcn_sched_barrier(0);

      for (int nd = 0; nd < 4; ++nd) {
        const u16* vp = VTb + ((size_t)bh * 64 + nd*16 + c) * SP + k0 + 8*g;
        o[nd] = mfma_bf16(ap, *(const bf16x8*)vp, o[nd]);
      }
    }

    for (int nd = 0; nd < 4; ++nd)
      for (int r = 0; r < 4; ++r) {
        const float v = o[nd][r] / ls[r];
        out[((size_t)b * SS + qrow[r]) * DD + hh*64 + nd*16 + c] = f2b(v);
      }
    return;
  }

  // staged path: 2 q-tiles per wave, 4 waves; rows are all input rows (< nin)
  const int sb = blockIdx.x - NTAIL;      // [0, 1024)
  const int bh = sb & 127;
  const int qg = sb >> 7;                 // 0..7
  const int b = bh >> 4, hh = bh & 15;

  const u16 *ssrc0, *ssrc1; int kstr; u16 *sdst0, *sdst1;
  if (tid < 128) {
    const int i0 = tid, i1 = tid + 128;
    const int r0 = i0 >> 3, cg0 = (i0 & 7) ^ (r0 & 7);
    const int r1 = i1 >> 3, cg1 = (i1 & 7) ^ (r1 & 7);
    ssrc0 = Kb + ((size_t)bh * SP + r0) * 64 + cg0 * 8;
    ssrc1 = Kb + ((size_t)bh * SP + r1) * 64 + cg1 * 8;
    kstr = 32 * 64;
    sdst0 = &KV[0][i0 * 8];
    sdst1 = &KV[0][i1 * 8];
  } else {
    const int t2 = tid - 128;
    const int i0 = t2, i1 = t2 + 128;
    const int r0 = i0 >> 2, cg0 = (i0 & 3) ^ (r0 & 3);
    const int r1 = i1 >> 2, cg1 = (i1 & 3) ^ (r1 & 3);
    ssrc0 = VTb + ((size_t)bh * 64 + r0) * SP + cg0 * 8;
    ssrc1 = VTb + ((size_t)bh * 64 + r1) * SP + cg1 * 8;
    kstr = 32;
    sdst0 = &KV[0][2048 + i0 * 8];
    sdst1 = &KV[0][2048 + i1 * 8];
  }
#define STAGE(bufbit, kt) do { \
    gload_lds16(ssrc0 + (size_t)(kt) * kstr, sdst0 + (bufbit) * 4096); \
    gload_lds16(ssrc1 + (size_t)(kt) * kstr, sdst1 + (bufbit) * 4096); } while (0)

  bf16x8 aq[2][2];
  int q0[2];
#pragma unroll
  for (int qq = 0; qq < 2; ++qq) {
    q0[qq] = (qg * 8 + w * 2 + qq) * 16;
    const u16* qp = Qb + ((size_t)bh * SP + q0[qq] + c) * 64 + g * 8;
    aq[qq][0] = *(const bf16x8*)qp;
    aq[qq][1] = *(const bf16x8*)(qp + 32);
  }

  Bf8 onesf;
  for (int i = 0; i < 8; ++i) onesf.s[i] = (c == 0) ? (u16)0x3F80 : (u16)0;

  float m[2][4];
  f32x4 o[2][5];
#pragma unroll
  for (int qq = 0; qq < 2; ++qq) {
    for (int r = 0; r < 4; ++r) m[qq][r] = -1e30f;
    for (int nd = 0; nd < 5; ++nd) o[qq][nd] = f32x4{0.f,0.f,0.f,0.f};
  }
  const bool tregs0 = (q0[0] + 15) >= nin;
  const bool tregs1 = (q0[1] + 15) >= nin;
  const int c7 = c & 7, c3 = c & 3;

  STAGE(0, 0);

  for (int kt = 0; kt < 33; ++kt) {
    const int buf = kt & 1;
    __syncthreads();                   // buf staged (drains vmcnt) + prior-buf reads done
    if (kt < 32) STAGE(buf ^ 1, kt + 1);
    const u16* Kt = &KV[buf][0];
    const u16* Vt = &KV[buf][2048];
    const int k0 = kt * 32;

    // K fragments: loaded once, shared by both q-tiles
    bf16x8 k00 = *(const bf16x8*)(Kt + c*64        + ((g    ) ^ c7) * 8);
    bf16x8 k01 = *(const bf16x8*)(Kt + c*64        + ((g + 4) ^ c7) * 8);
    bf16x8 k10 = *(const bf16x8*)(Kt + (c+16)*64   + ((g    ) ^ c7) * 8);
    bf16x8 k11 = *(const bf16x8*)(Kt + (c+16)*64   + ((g + 4) ^ c7) * 8);

#pragma unroll
    for (int qq = 0; qq < 2; ++qq) {
      f32x4 s[2];
      {
        f32x4 z0 = f32x4{0.f,0.f,0.f,0.f};
        z0 = mfma_bf16(aq[qq][0], k00, z0);
        z0 = mfma_bf16(aq[qq][1], k01, z0);
        s[0] = z0;
        f32x4 z1 = f32x4{0.f,0.f,0.f,0.f};
        z1 = mfma_bf16(aq[qq][0], k10, z1);
        z1 = mfma_bf16(aq[qq][1], k11, z1);
        s[1] = z1;
      }

      const bool tregs = qq ? tregs1 : tregs0;
      if (tregs || (k0 + 31 >= SS)) {
        const int qr0 = q0[qq] + 4*g;
        for (int jt = 0; jt < 2; ++jt) {
          const int j = k0 + jt*16 + c;
          for (int r = 0; r < 4; ++r) {
            const int q = qr0 + r;
            const bool blocked = (j >= SS) || ((q >= nin) && (j >= nin) && (j > q));
            if (blocked) s[jt][r] = -1e30f;
          }
        }
      }

      // defer-max (T13, THR=8): only rescale o when the tile max grew past m+8.
      float t4[4];
      for (int r = 0; r < 4; ++r)
        t4[r] = dppmax16(fmaxf(s[0][r], s[1][r]));
      const bool need = (t4[0] > m[qq][0] + 8.f) || (t4[1] > m[qq][1] + 8.f) ||
                        (t4[2] > m[qq][2] + 8.f) || (t4[3] > m[qq][3] + 8.f);
      if (__any(need)) {
        for (int r = 0; r < 4; ++r) {
          const float mn = fmaxf(m[qq][r], t4[r]);
          const float al = __expf(m[qq][r] - mn);
          m[qq][r] = mn;
          for (int nd = 0; nd < 5; ++nd) o[qq][nd][r] *= al;
        }
      }
      for (int r = 0; r < 4; ++r) {
        s[0][r] = __expf(s[0][r] - m[qq][r]);
        s[1][r] = __expf(s[1][r] - m[qq][r]);
      }

      // P^T via per-wave LDS (in-wave DS ordering; sched_barrier pins program order)
      for (int jt = 0; jt < 2; ++jt)
        for (int r = 0; r < 4; ++r)
          pw[(4*g + r)*40 + jt*16 + c] = f2b(s[jt][r]);
      __builtin_amdgcn_sched_barrier(0);
      bf16x8 ap = *(const bf16x8*)(pw + c*40 + 8*g);
      __builtin_amdgcn_sched_barrier(0);

      for (int nd = 0; nd < 4; ++nd) {
        bf16x8 bv = *(const bf16x8*)(Vt + (nd*16 + c)*32 + ((g ^ c3) * 8));
        o[qq][nd] = mfma_bf16(ap, bv, o[qq][nd]);
      }
      o[qq][4] = mfma_bf16(ap, onesf.v, o[qq][4]);   // ls accumulates in column 0
    }
  }
#undef STAGE

#pragma unroll
  for (int qq = 0; qq < 2; ++qq) {
    float rls[4];
    for (int r = 0; r < 4; ++r)
      rls[r] = 1.0f / __shfl(o[qq][4][r], lane & 48);
    const int qr0 = q0[qq] + 4*g;
    for (int nd = 0; nd < 4; ++nd)
      for (int r = 0; r < 4; ++r)
        out[((size_t)b * SS + qr0 + r) * DD + hh*64 + nd*16 + c] = f2b(o[qq][nd][r] * rls[r]);
  }
}

// ---------------------------------------------------------------------------------------
extern "C" void kernel_launch(void* const* d_in, const int* in_sizes, int n_in,
                              void* d_out, int out_size, void* d_ws, size_t ws_size,
                              hipStream_t stream) {
  const float* x    = (const float*)d_in[0];
  const int*   npt  = (const int*)  d_in[1];
  const float* ln1g = (const float*)d_in[2];
  const float* ln1b = (const float*)d_in[3];
  const float* wqkv = (const float*)d_in[4];
  const float* bqkv = (const float*)d_in[5];
  const float* wo   = (const float*)d_in[6];
  const float* bo   = (const float*)d_in[7];
  const float* ln2g = (const float*)d_in[8];
  const float* ln2b = (const float*)d_in[9];
  const float* w1   = (const float*)d_in[10];
  const float* b1   = (const float*)d_in[11];
  const float* w2   = (const float*)d_in[12];
  const float* b2   = (const float*)d_in[13];
  const float* lnfg = (const float*)d_in[14];
  const float* lnfb = (const float*)d_in[15];

  char* ws = (char*)d_ws;
  size_t off = 0;
  u16*   wqkvT = (u16*)(ws + off);   off += (size_t)NL*TD*DD*2;
  u16*   woT   = (u16*)(ws + off);   off += (size_t)NL*DD*DD*2;
  u16*   w1T   = (u16*)(ws + off);   off += (size_t)NL*DFFN*DD*2;
  u16*   w2T   = (u16*)(ws + off);   off += (size_t)NL*DD*DFFN*2;
  float* h     = (float*)(ws + off); off += (size_t)MM*DD*4;
  u16*   lnb   = (u16*)(ws + off);   off += (size_t)MM*DD*2;
  u16*   Qb    = (u16*)(ws + off);   off += (size_t)BB*HH*SP*64*2;
  u16*   Kb    = (u16*)(ws + off);   off += (size_t)BB*HH*SP*64*2;
  u16*   VTb   = (u16*)(ws + off);   off += (size_t)BB*HH*64*SP*2;
  u16*   attnO = (u16*)(ws + off);   off += (size_t)MM*DD*2;
  u16*   ffh   = (u16*)(ws + off);   off += (size_t)MM*DFFN*2;
  float* P0    = (float*)(ws + off); off += (size_t)MM*DD*4;
  float* P1    = (float*)(ws + off); off += (size_t)MM*DD*4;

  const dim3 tb(32, 8);
  transpose_cast<<<dim3(TD/32,   DD/32,   NL), tb, 0, stream>>>(wqkv, wqkvT, DD,   TD);
  transpose_cast<<<dim3(DD/32,   DD/32,   NL), tb, 0, stream>>>(wo,   woT,   DD,   DD);
  transpose_cast<<<dim3(DFFN/32, DD/32,   NL), tb, 0, stream>>>(w1,   w1T,   DD,   DFFN);
  transpose_cast<<<dim3(DD/32,   DFFN/32, NL), tb, 0, stream>>>(w2,   w2T,   DFFN, DD);
  hipMemcpyAsync(h, x, (size_t)MM*DD*4, hipMemcpyDeviceToDevice, stream);
  hipMemsetAsync(Qb, 0, (size_t)3*BB*HH*SP*64*2, stream);   // zero Q/K/VT arena (pads)

  for (int l = 0; l < NL; ++l) {
    if (l == 0)
      ln_kernel<<<MM, 256, 0, stream>>>(h, ln1g, ln1b, lnb);
    else
      ln_comb<0><<<MM, 256, 0, stream>>>(P0, P1, h, ln1g + (size_t)l*DD, ln1b + (size_t)l*DD,
                                         lnb, nullptr);
    gemm_bt<3><<<dim3(MM/128, TD/128), 256, 0, stream>>>(
        lnb, wqkvT + (size_t)l*TD*DD, bqkv + (size_t)l*TD, nullptr,
        Qb, Kb, VTb, TD, DD);
    attn_staged<<<dim3(1024 + NTAIL), 256, 0, stream>>>(Qb, Kb, VTb, attnO, npt);
    gemm_splitk<<<dim3(MM/128, DD/128, 2), 256, 0, stream>>>(
        attnO, woT + (size_t)l*DD*DD, bo + (size_t)l*DD, h, P0, P1, DD, DD);
    ln_comb<0><<<MM, 256, 0, stream>>>(P0, P1, h, ln2g + (size_t)l*DD, ln2b + (size_t)l*DD,
                                       lnb, nullptr);
    gemm_bt<1><<<dim3(MM/128, DFFN/128), 256, 0, stream>>>(
        lnb, w1T + (size_t)l*DFFN*DD, b1 + (size_t)l*DFFN, ffh,
        nullptr, nullptr, nullptr, DFFN, DD);
    gemm_splitk<<<dim3(MM/128, DD/128, 2), 256, 0, stream>>>(
        ffh, w2T + (size_t)l*DD*DFFN, b2 + (size_t)l*DD, h, P0, P1, DD, DFFN);
  }
  ln_comb<1><<<MM, 256, 0, stream>>>(P0, P1, h, lnfg, lnfb, nullptr, (float*)d_out);
}

// Round 22
// 5709.492 us; speedup vs baseline: 1.0339x; 1.0339x over previous
//
#include <hip/hip_runtime.h>
#include <hip/hip_bf16.h>
#include <stdint.h>

#define DD   1024
#define TD   3072
#define DFFN 4096
#define NL   12
#define SS   1040
#define SP   1056          /* padded seq for attention operand arena */
#define BB   8
#define MM   (BB*SS)       /* 8320 */
#define HH   16
#define NTAIL 32           /* leading tail blocks in attn_staged grid (4 waves each) */

typedef float  f32x4  __attribute__((ext_vector_type(4)));
typedef __bf16 bf16x8 __attribute__((ext_vector_type(8)));
typedef unsigned short u16;

union Bf8 { bf16x8 v; u16 s[8]; };

__device__ __forceinline__ u16 f2b(float f) {
  union { float f; unsigned u; } x; x.f = f;
  unsigned r = (x.u + 0x7FFFu + ((x.u >> 16) & 1u)) >> 16;
  return (u16)r;
}

__device__ __forceinline__ f32x4 mfma_bf16(bf16x8 a, bf16x8 b, f32x4 c) {
  return __builtin_amdgcn_mfma_f32_16x16x32_bf16(a, b, c, 0, 0, 0);
}

__device__ __forceinline__ void gload_lds16(const u16* g, u16* l) {
  __builtin_amdgcn_global_load_lds((const __attribute__((address_space(1))) void*)g,
                                   (__attribute__((address_space(3))) void*)l, 16, 0, 0);
}

// 16-lane max reduce via DPP (quad_perm xor1, xor2, row_ror:4, row_ror:8) — VALU-speed.
__device__ __forceinline__ float dppmax16(float t) {
  union { float f; int i; } u, v;
  u.f = t;
  v.i = __builtin_amdgcn_update_dpp(0, u.i, 0xB1, 0xF, 0xF, true);   // quad_perm [1,0,3,2]
  u.f = fmaxf(u.f, v.f);
  v.i = __builtin_amdgcn_update_dpp(0, u.i, 0x4E, 0xF, 0xF, true);   // quad_perm [2,3,0,1]
  u.f = fmaxf(u.f, v.f);
  v.i = __builtin_amdgcn_update_dpp(0, u.i, 0x124, 0xF, 0xF, true);  // row_ror:4
  u.f = fmaxf(u.f, v.f);
  v.i = __builtin_amdgcn_update_dpp(0, u.i, 0x128, 0xF, 0xF, true);  // row_ror:8
  u.f = fmaxf(u.f, v.f);
  return u.f;
}

// ---------------- weight cast+transpose: in (K,N) f32 -> out (N,K) bf16, per layer z ----
__global__ __launch_bounds__(256)
void transpose_cast(const float* __restrict__ in, u16* __restrict__ out, int K, int N) {
  __shared__ float tile[32][33];
  const int n0 = blockIdx.x * 32, k0 = blockIdx.y * 32;
  const size_t lb = (size_t)blockIdx.z * K * N;
  const int tx = threadIdx.x, ty = threadIdx.y;
  for (int j = 0; j < 4; ++j)
    tile[ty + 8*j][tx] = in[lb + (size_t)(k0 + ty + 8*j) * N + n0 + tx];
  __syncthreads();
  for (int j = 0; j < 4; ++j)
    out[lb + (size_t)(n0 + ty + 8*j) * K + k0 + tx] = f2b(tile[tx][ty + 8*j]);
}

// ---------------- LayerNorm: row of 1024 -> bf16 out --------------------------------
__global__ __launch_bounds__(256)
void ln_kernel(const float* __restrict__ in, const float* __restrict__ gam,
               const float* __restrict__ bet, u16* __restrict__ outb) {
  const int row = blockIdx.x, t = threadIdx.x;
  const float4 v = ((const float4*)(in + (size_t)row * DD))[t];
  float s  = v.x + v.y + v.z + v.w;
  float s2 = v.x*v.x + v.y*v.y + v.z*v.z + v.w*v.w;
  for (int off = 1; off < 64; off <<= 1) { s += __shfl_xor(s, off); s2 += __shfl_xor(s2, off); }
  __shared__ float red[8];
  if ((t & 63) == 0) { red[t >> 6] = s; red[4 + (t >> 6)] = s2; }
  __syncthreads();
  s  = red[0] + red[1] + red[2] + red[3];
  s2 = red[4] + red[5] + red[6] + red[7];
  const float mu = s * (1.0f/1024.0f);
  const float var = s2 * (1.0f/1024.0f) - mu*mu;
  const float rs = rsqrtf(var + 1e-6f);
  const float4 gv = ((const float4*)gam)[t];
  const float4 bv = ((const float4*)bet)[t];
  ushort4 o;
  o.x = f2b((v.x - mu)*rs*gv.x + bv.x);
  o.y = f2b((v.y - mu)*rs*gv.y + bv.y);
  o.z = f2b((v.z - mu)*rs*gv.z + bv.z);
  o.w = f2b((v.w - mu)*rs*gv.w + bv.w);
  ((ushort4*)(outb + (size_t)row * DD))[t] = o;
}

// ---------------- LN with split-K combine: x = P0 + P1; writes h (resid) + LN out -----
// OUTF=0: bf16 LN out.  OUTF=1: f32 LN out (final).
template<int OUTF>
__global__ __launch_bounds__(256)
void ln_comb(const float* __restrict__ P0, const float* __restrict__ P1,
             float* __restrict__ hout, const float* __restrict__ gam,
             const float* __restrict__ bet, u16* __restrict__ outb,
             float* __restrict__ outf) {
  const int row = blockIdx.x, t = threadIdx.x;
  const float4 a = ((const float4*)(P0 + (size_t)row * DD))[t];
  const float4 b = ((const float4*)(P1 + (size_t)row * DD))[t];
  float4 v; v.x = a.x + b.x; v.y = a.y + b.y; v.z = a.z + b.z; v.w = a.w + b.w;
  ((float4*)(hout + (size_t)row * DD))[t] = v;
  float s  = v.x + v.y + v.z + v.w;
  float s2 = v.x*v.x + v.y*v.y + v.z*v.z + v.w*v.w;
  for (int off = 1; off < 64; off <<= 1) { s += __shfl_xor(s, off); s2 += __shfl_xor(s2, off); }
  __shared__ float red[8];
  if ((t & 63) == 0) { red[t >> 6] = s; red[4 + (t >> 6)] = s2; }
  __syncthreads();
  s  = red[0] + red[1] + red[2] + red[3];
  s2 = red[4] + red[5] + red[6] + red[7];
  const float mu = s * (1.0f/1024.0f);
  const float var = s2 * (1.0f/1024.0f) - mu*mu;
  const float rs = rsqrtf(var + 1e-6f);
  const float4 gv = ((const float4*)gam)[t];
  const float4 bv = ((const float4*)bet)[t];
  const float y0 = (v.x - mu)*rs*gv.x + bv.x;
  const float y1 = (v.y - mu)*rs*gv.y + bv.y;
  const float y2 = (v.z - mu)*rs*gv.z + bv.z;
  const float y3 = (v.w - mu)*rs*gv.w + bv.w;
  if (OUTF) {
    float4 o; o.x=y0; o.y=y1; o.z=y2; o.w=y3;
    ((float4*)(outf + (size_t)row * DD))[t] = o;
  } else {
    ushort4 o; o.x=f2b(y0); o.y=f2b(y1); o.z=f2b(y2); o.w=f2b(y3);
    ((ushort4*)(outb + (size_t)row * DD))[t] = o;
  }
}

// ---------------- 128² GEMM: C(M,N) = A(M,K)bf16 @ Bt(N,K)bf16^T + bias [+ epi] --------
// EPI 1: gelu, write bf16.  EPI 2: +resid, write f32.  EPI 3: qkv scatter.
// nb-fastest decode: consecutive (same-XCD) blocks share the A-panel. 4 blocks/CU.
template<int EPI>
__global__ __launch_bounds__(256, 4)
void gemm_bt(const u16* __restrict__ A, const u16* __restrict__ Bt,
             const float* __restrict__ bias, const float* __restrict__ resid,
             float* outF, u16* outB,
             u16* __restrict__ qb, u16* __restrict__ kb, u16* __restrict__ vtb,
             int N, int K) {
  __shared__ u16 As[128*64];
  __shared__ u16 Bs[128*64];
  const int tid = threadIdx.x;

  const int nwg = gridDim.x * gridDim.y;
  int wgid = blockIdx.y * gridDim.x + blockIdx.x;
  wgid = (wgid & 7) * (nwg >> 3) + (wgid >> 3);
  const int nb = wgid % gridDim.y;
  const int mb = wgid / gridDim.y;
  const int m0 = mb * 128, n0 = nb * 128;

  const int lane = tid & 63, w = tid >> 6;
  const int wr = (w >> 1) * 64, wc = (w & 1) * 64;
  const int c = lane & 15, g = lane >> 4;

  f32x4 acc[4][4];
  for (int i = 0; i < 4; ++i) for (int j = 0; j < 4; ++j) acc[i][j] = f32x4{0.f,0.f,0.f,0.f};

  const int srow = tid >> 3, scg = tid & 7;
  const size_t aoff = (size_t)(m0 + srow) * K + scg * 8;
  const size_t boff = (size_t)(n0 + srow) * K + scg * 8;

  for (int kt = 0; kt < K; kt += 64) {
    for (int it = 0; it < 4; ++it) {
      gload_lds16(A  + aoff + (size_t)it * 32 * K + kt, As + (it*256 + tid) * 8);
      gload_lds16(Bt + boff + (size_t)it * 32 * K + kt, Bs + (it*256 + tid) * 8);
    }
    __syncthreads();
    for (int kk = 0; kk < 2; ++kk) {
      bf16x8 af[4], bfr[4];
      for (int i = 0; i < 4; ++i) af[i]  = *(const bf16x8*)(As + (wr + i*16 + c)*64 + kk*32 + g*8);
      for (int j = 0; j < 4; ++j) bfr[j] = *(const bf16x8*)(Bs + (wc + j*16 + c)*64 + kk*32 + g*8);
      for (int i = 0; i < 4; ++i)
        for (int j = 0; j < 4; ++j)
          acc[i][j] = mfma_bf16(af[i], bfr[j], acc[i][j]);
    }
    __syncthreads();
  }

  for (int j = 0; j < 4; ++j) {
    const int col = n0 + wc + j*16 + c;
    const float bcol = bias[col];
    for (int i = 0; i < 4; ++i) {
      const int row0 = m0 + wr + i*16 + 4*g;
      if (EPI == 3) {
        const int part = col >> 10;
        const int hh2  = (col >> 6) & 15;
        const int hd   = col & 63;
        const int bb   = (int)((unsigned)row0 / SS);
        const int s0   = row0 - bb * SS;          // 4-aligned; never crosses batch
        const size_t bh = (size_t)(bb * HH + hh2);
        if (part == 2) {
          ushort4 pk;
          pk.x = f2b(acc[i][j][0] + bcol);
          pk.y = f2b(acc[i][j][1] + bcol);
          pk.z = f2b(acc[i][j][2] + bcol);
          pk.w = f2b(acc[i][j][3] + bcol);
          *(ushort4*)(vtb + (bh*64 + hd)*SP + s0) = pk;
        } else if (part == 0) {
          for (int r = 0; r < 4; ++r)
            qb[(bh*SP + s0 + r)*64 + hd] = f2b((acc[i][j][r] + bcol) * 0.125f);
        } else {
          for (int r = 0; r < 4; ++r)
            kb[(bh*SP + s0 + r)*64 + hd] = f2b(acc[i][j][r] + bcol);
        }
      } else {
        for (int r = 0; r < 4; ++r) {
          const size_t idx = (size_t)(row0 + r) * N + col;
          const float v = acc[i][j][r] + bcol;
          if (EPI == 1) {
            const float z = 1.5957691216f * (v + 0.044715f * v * v * v);
            const float e = __expf(z);
            outB[idx] = f2b(v * e * __builtin_amdgcn_rcpf(e + 1.0f));
          } else {
            outF[idx] = v + resid[idx];
          }
        }
      }
    }
  }
}

// ---------------- FFN2 GEMM, split-K across blocks (blockIdx.z = K-half) --------------
// kh=0 writes P0 = acc(K-half 0) + bias + resid; kh=1 writes P1 = acc(K-half 1).
// Combine happens in the next layer's ln_comb. Grid 65 x 8 x 2 = 1040 blocks (4.06/CU).
__global__ __launch_bounds__(256, 4)
void gemm_ffn2(const u16* __restrict__ A, const u16* __restrict__ Bt,
               const float* __restrict__ bias, const float* __restrict__ resid,
               float* __restrict__ P0, float* __restrict__ P1, int N, int K) {
  __shared__ u16 As[128*64];
  __shared__ u16 Bs[128*64];
  const int tid = threadIdx.x;
  const int kh = blockIdx.z;

  const int nwg = gridDim.x * gridDim.y;
  int wgid = blockIdx.y * gridDim.x + blockIdx.x;
  wgid = (wgid & 7) * (nwg >> 3) + (wgid >> 3);
  const int nb = wgid % gridDim.y;
  const int mb = wgid / gridDim.y;
  const int m0 = mb * 128, n0 = nb * 128;

  const int lane = tid & 63, w = tid >> 6;
  const int wr = (w >> 1) * 64, wc = (w & 1) * 64;
  const int c = lane & 15, g = lane >> 4;

  f32x4 acc[4][4];
  for (int i = 0; i < 4; ++i) for (int j = 0; j < 4; ++j) acc[i][j] = f32x4{0.f,0.f,0.f,0.f};

  const int KH = K >> 1;
  const int srow = tid >> 3, scg = tid & 7;
  const size_t aoff = (size_t)(m0 + srow) * K + scg * 8 + (size_t)kh * KH;
  const size_t boff = (size_t)(n0 + srow) * K + scg * 8 + (size_t)kh * KH;

  for (int kt = 0; kt < KH; kt += 64) {
    for (int it = 0; it < 4; ++it) {
      gload_lds16(A  + aoff + (size_t)it * 32 * K + kt, As + (it*256 + tid) * 8);
      gload_lds16(Bt + boff + (size_t)it * 32 * K + kt, Bs + (it*256 + tid) * 8);
    }
    __syncthreads();
    for (int kk = 0; kk < 2; ++kk) {
      bf16x8 af[4], bfr[4];
      for (int i = 0; i < 4; ++i) af[i]  = *(const bf16x8*)(As + (wr + i*16 + c)*64 + kk*32 + g*8);
      for (int j = 0; j < 4; ++j) bfr[j] = *(const bf16x8*)(Bs + (wc + j*16 + c)*64 + kk*32 + g*8);
      for (int i = 0; i < 4; ++i)
        for (int j = 0; j < 4; ++j)
          acc[i][j] = mfma_bf16(af[i], bfr[j], acc[i][j]);
    }
    __syncthreads();
  }

  float* outP = kh ? P1 : P0;
  for (int j = 0; j < 4; ++j) {
    const int col = n0 + wc + j*16 + c;
    const float bcol = kh ? 0.f : bias[col];
    for (int i = 0; i < 4; ++i) {
      const int row0 = m0 + wr + i*16 + 4*g;
      for (int r = 0; r < 4; ++r) {
        const size_t idx = (size_t)(row0 + r) * N + col;
        float v = acc[i][j][r] + bcol;
        if (!kh) v += resid[idx];
        outP[idx] = v;
      }
    }
  }
}

// ---------------- 64x128-tile GEMM for WO (N=1024, K=1024): +resid, f32 out -----------
__global__ __launch_bounds__(256, 4)
void gemm64(const u16* __restrict__ A, const u16* __restrict__ Bt,
            const float* __restrict__ bias, const float* __restrict__ resid,
            float* __restrict__ outF, int N, int K) {
  __shared__ u16 As[64*64];
  __shared__ u16 Bs[128*64];
  const int tid = threadIdx.x;

  const int nwg = gridDim.x * gridDim.y;
  int wgid = blockIdx.y * gridDim.x + blockIdx.x;
  wgid = (wgid & 7) * (nwg >> 3) + (wgid >> 3);
  const int nb = wgid % gridDim.y;
  const int mb = wgid / gridDim.y;
  const int m0 = mb * 64, n0 = nb * 128;

  const int lane = tid & 63, w = tid >> 6;
  const int wr = (w >> 1) * 32, wc = (w & 1) * 64;
  const int c = lane & 15, g = lane >> 4;

  f32x4 acc[2][4];
  for (int i = 0; i < 2; ++i) for (int j = 0; j < 4; ++j) acc[i][j] = f32x4{0.f,0.f,0.f,0.f};

  const int srow = tid >> 3, scg = tid & 7;
  const size_t aoff = (size_t)(m0 + srow) * K + scg * 8;
  const size_t boff = (size_t)(n0 + srow) * K + scg * 8;

  for (int kt = 0; kt < K; kt += 64) {
    for (int it = 0; it < 2; ++it)
      gload_lds16(A  + aoff + (size_t)it * 32 * K + kt, As + (it*256 + tid) * 8);
    for (int it = 0; it < 4; ++it)
      gload_lds16(Bt + boff + (size_t)it * 32 * K + kt, Bs + (it*256 + tid) * 8);
    __syncthreads();
    for (int kk = 0; kk < 2; ++kk) {
      bf16x8 af[2], bfr[4];
      for (int i = 0; i < 2; ++i) af[i]  = *(const bf16x8*)(As + (wr + i*16 + c)*64 + kk*32 + g*8);
      for (int j = 0; j < 4; ++j) bfr[j] = *(const bf16x8*)(Bs + (wc + j*16 + c)*64 + kk*32 + g*8);
      for (int i = 0; i < 2; ++i)
        for (int j = 0; j < 4; ++j)
          acc[i][j] = mfma_bf16(af[i], bfr[j], acc[i][j]);
    }
    __syncthreads();
  }

  for (int j = 0; j < 4; ++j) {
    const int col = n0 + wc + j*16 + c;
    const float bcol = bias[col];
    for (int i = 0; i < 2; ++i) {
      const int row0 = m0 + wr + i*16 + 4*g;
      for (int r = 0; r < 4; ++r) {
        const size_t idx = (size_t)(row0 + r) * N + col;
        outF[idx] = acc[i][j][r] + bcol + resid[idx];
      }
    }
  }
}

// ---------------- staged attention + fused tail; 256-thr blocks, 2 q-tiles/wave -------
__global__ __launch_bounds__(256, 4)
void attn_staged(const u16* __restrict__ Qb, const u16* __restrict__ Kb,
                 const u16* __restrict__ VTb, u16* __restrict__ out,
                 const int* __restrict__ npt) {
  __shared__ u16 KV[2][4096];       // per buf: [0..2048) K tile, [2048..4096) V tile
  __shared__ u16 PT[4][640];        // per-wave P^T, 16 rows x 40 u16 (bf16)
  const int tid = threadIdx.x;
  const int w = tid >> 6, lane = tid & 63;
  const int c = lane & 15, g = lane >> 4;
  const int nin = npt[0];
  u16* pw = PT[w];

  if (blockIdx.x < NTAIL) {
    const int bh = blockIdx.x * 4 + w;
    const int b = bh >> 4, hh = bh & 15;
    const int q0 = 64 * 16;

    bf16x8 aq0, aq1;
    {
      const u16* qp = Qb + ((size_t)bh * SP + q0 + c) * 64 + g * 8;
      aq0 = *(const bf16x8*)qp;
      aq1 = *(const bf16x8*)(qp + 32);
    }

    float m[4], ls[4];
    f32x4 o[4];
    int qrow[4];
    for (int r = 0; r < 4; ++r) { m[r] = -1e30f; ls[r] = 0.f; qrow[r] = q0 + 4*g + r; }
    for (int nd = 0; nd < 4; ++nd) o[nd] = f32x4{0.f,0.f,0.f,0.f};

    for (int kt = 0; kt < 33; ++kt) {
      const int k0 = kt * 32;

      f32x4 s[2];
      {
        const u16* kp0 = Kb + ((size_t)bh * SP + k0 + c) * 64 + g * 8;
        f32x4 z0 = f32x4{0.f,0.f,0.f,0.f};
        z0 = mfma_bf16(aq0, *(const bf16x8*)kp0, z0);
        z0 = mfma_bf16(aq1, *(const bf16x8*)(kp0 + 32), z0);
        s[0] = z0;
        const u16* kp1 = kp0 + 16 * 64;
        f32x4 z1 = f32x4{0.f,0.f,0.f,0.f};
        z1 = mfma_bf16(aq0, *(const bf16x8*)kp1, z1);
        z1 = mfma_bf16(aq1, *(const bf16x8*)(kp1 + 32), z1);
        s[1] = z1;
      }

      for (int jt = 0; jt < 2; ++jt) {
        const int j = k0 + jt*16 + c;
        for (int r = 0; r < 4; ++r) {
          const int q = qrow[r];
          const bool blocked = (j >= SS) || ((q >= nin) && (j >= nin) && (j > q));
          if (blocked) s[jt][r] = -1e30f;
        }
      }

      for (int r = 0; r < 4; ++r) {
        float t = fmaxf(s[0][r], s[1][r]);
        for (int off = 1; off < 16; off <<= 1) t = fmaxf(t, __shfl_xor(t, off));
        const float mn = fmaxf(m[r], t);
        const float al = __expf(m[r] - mn);
        m[r] = mn;
        const float p0 = __expf(s[0][r] - mn);
        const float p1 = __expf(s[1][r] - mn);
        s[0][r] = p0; s[1][r] = p1;
        float ps = p0 + p1;
        for (int off = 1; off < 16; off <<= 1) ps += __shfl_xor(ps, off);
        ls[r] = ls[r] * al + ps;
        for (int nd = 0; nd < 4; ++nd) o[nd][r] *= al;
      }

      for (int jt = 0; jt < 2; ++jt)
        for (int r = 0; r < 4; ++r)
          pw[(4*g + r)*40 + jt*16 + c] = f2b(s[jt][r]);
      __builtin_amdgcn_sched_barrier(0);
      bf16x8 ap = *(const bf16x8*)(pw + c*40 + 8*g);
      __builtin_amdgcn_sched_barrier(0);

      for (int nd = 0; nd < 4; ++nd) {
        const u16* vp = VTb + ((size_t)bh * 64 + nd*16 + c) * SP + k0 + 8*g;
        o[nd] = mfma_bf16(ap, *(const bf16x8*)vp, o[nd]);
      }
    }

    for (int nd = 0; nd < 4; ++nd)
      for (int r = 0; r < 4; ++r) {
        const float v = o[nd][r] / ls[r];
        out[((size_t)b * SS + qrow[r]) * DD + hh*64 + nd*16 + c] = f2b(v);
      }
    return;
  }

  // staged path: 2 q-tiles per wave, 4 waves
  const int sb = blockIdx.x - NTAIL;      // [0, 1024)
  const int bh = sb & 127;
  const int qg = sb >> 7;                 // 0..7
  const int b = bh >> 4, hh = bh & 15;

  const u16 *ssrc0, *ssrc1; int kstr; u16 *sdst0, *sdst1;
  if (tid < 128) {
    const int i0 = tid, i1 = tid + 128;
    const int r0 = i0 >> 3, cg0 = (i0 & 7) ^ (r0 & 7);
    const int r1 = i1 >> 3, cg1 = (i1 & 7) ^ (r1 & 7);
    ssrc0 = Kb + ((size_t)bh * SP + r0) * 64 + cg0 * 8;
    ssrc1 = Kb + ((size_t)bh * SP + r1) * 64 + cg1 * 8;
    kstr = 32 * 64;
    sdst0 = &KV[0][i0 * 8];
    sdst1 = &KV[0][i1 * 8];
  } else {
    const int t2 = tid - 128;
    const int i0 = t2, i1 = t2 + 128;
    const int r0 = i0 >> 2, cg0 = (i0 & 3) ^ (r0 & 3);
    const int r1 = i1 >> 2, cg1 = (i1 & 3) ^ (r1 & 3);
    ssrc0 = VTb + ((size_t)bh * 64 + r0) * SP + cg0 * 8;
    ssrc1 = VTb + ((size_t)bh * 64 + r1) * SP + cg1 * 8;
    kstr = 32;
    sdst0 = &KV[0][2048 + i0 * 8];
    sdst1 = &KV[0][2048 + i1 * 8];
  }
#define STAGE(bufbit, kt) do { \
    gload_lds16(ssrc0 + (size_t)(kt) * kstr, sdst0 + (bufbit) * 4096); \
    gload_lds16(ssrc1 + (size_t)(kt) * kstr, sdst1 + (bufbit) * 4096); } while (0)

  bf16x8 aq[2][2];
  int q0[2];
#pragma unroll
  for (int qq = 0; qq < 2; ++qq) {
    q0[qq] = (qg * 8 + w * 2 + qq) * 16;
    const u16* qp = Qb + ((size_t)bh * SP + q0[qq] + c) * 64 + g * 8;
    aq[qq][0] = *(const bf16x8*)qp;
    aq[qq][1] = *(const bf16x8*)(qp + 32);
  }

  Bf8 onesf;
  for (int i = 0; i < 8; ++i) onesf.s[i] = (c == 0) ? (u16)0x3F80 : (u16)0;

  float m[2][4];
  f32x4 o[2][5];
#pragma unroll
  for (int qq = 0; qq < 2; ++qq) {
    for (int r = 0; r < 4; ++r) m[qq][r] = -1e30f;
    for (int nd = 0; nd < 5; ++nd) o[qq][nd] = f32x4{0.f,0.f,0.f,0.f};
  }
  const bool tregs0 = (q0[0] + 15) >= nin;
  const bool tregs1 = (q0[1] + 15) >= nin;
  const int c7 = c & 7, c3 = c & 3;

  STAGE(0, 0);

  for (int kt = 0; kt < 33; ++kt) {
    const int buf = kt & 1;
    __syncthreads();
    if (kt < 32) STAGE(buf ^ 1, kt + 1);
    const u16* Kt = &KV[buf][0];
    const u16* Vt = &KV[buf][2048];
    const int k0 = kt * 32;

    bf16x8 k00 = *(const bf16x8*)(Kt + c*64        + ((g    ) ^ c7) * 8);
    bf16x8 k01 = *(const bf16x8*)(Kt + c*64        + ((g + 4) ^ c7) * 8);
    bf16x8 k10 = *(const bf16x8*)(Kt + (c+16)*64   + ((g    ) ^ c7) * 8);
    bf16x8 k11 = *(const bf16x8*)(Kt + (c+16)*64   + ((g + 4) ^ c7) * 8);

#pragma unroll
    for (int qq = 0; qq < 2; ++qq) {
      f32x4 s[2];
      {
        f32x4 z0 = f32x4{0.f,0.f,0.f,0.f};
        z0 = mfma_bf16(aq[qq][0], k00, z0);
        z0 = mfma_bf16(aq[qq][1], k01, z0);
        s[0] = z0;
        f32x4 z1 = f32x4{0.f,0.f,0.f,0.f};
        z1 = mfma_bf16(aq[qq][0], k10, z1);
        z1 = mfma_bf16(aq[qq][1], k11, z1);
        s[1] = z1;
      }

      const bool tregs = qq ? tregs1 : tregs0;
      if (tregs || (k0 + 31 >= SS)) {
        const int qr0 = q0[qq] + 4*g;
        for (int jt = 0; jt < 2; ++jt) {
          const int j = k0 + jt*16 + c;
          for (int r = 0; r < 4; ++r) {
            const int q = qr0 + r;
            const bool blocked = (j >= SS) || ((q >= nin) && (j >= nin) && (j > q));
            if (blocked) s[jt][r] = -1e30f;
          }
        }
      }

      for (int r = 0; r < 4; ++r) {
        const float t = dppmax16(fmaxf(s[0][r], s[1][r]));
        const float mn = fmaxf(m[qq][r], t);
        const float al = __expf(m[qq][r] - mn);
        m[qq][r] = mn;
        for (int nd = 0; nd < 5; ++nd) o[qq][nd][r] *= al;
        s[0][r] = __expf(s[0][r] - mn);
        s[1][r] = __expf(s[1][r] - mn);
      }

      for (int jt = 0; jt < 2; ++jt)
        for (int r = 0; r < 4; ++r)
          pw[(4*g + r)*40 + jt*16 + c] = f2b(s[jt][r]);
      __builtin_amdgcn_sched_barrier(0);
      bf16x8 ap = *(const bf16x8*)(pw + c*40 + 8*g);
      __builtin_amdgcn_sched_barrier(0);

      for (int nd = 0; nd < 4; ++nd) {
        bf16x8 bv = *(const bf16x8*)(Vt + (nd*16 + c)*32 + ((g ^ c3) * 8));
        o[qq][nd] = mfma_bf16(ap, bv, o[qq][nd]);
      }
      o[qq][4] = mfma_bf16(ap, onesf.v, o[qq][4]);   // ls accumulates in column 0
    }
  }
#undef STAGE

#pragma unroll
  for (int qq = 0; qq < 2; ++qq) {
    float rls[4];
    for (int r = 0; r < 4; ++r)
      rls[r] = 1.0f / __shfl(o[qq][4][r], lane & 48);
    const int qr0 = q0[qq] + 4*g;
    for (int nd = 0; nd < 4; ++nd)
      for (int r = 0; r < 4; ++r)
        out[((size_t)b * SS + qr0 + r) * DD + hh*64 + nd*16 + c] = f2b(o[qq][nd][r] * rls[r]);
  }
}

// ---------------------------------------------------------------------------------------
extern "C" void kernel_launch(void* const* d_in, const int* in_sizes, int n_in,
                              void* d_out, int out_size, void* d_ws, size_t ws_size,
                              hipStream_t stream) {
  const float* x    = (const float*)d_in[0];
  const int*   npt  = (const int*)  d_in[1];
  const float* ln1g = (const float*)d_in[2];
  const float* ln1b = (const float*)d_in[3];
  const float* wqkv = (const float*)d_in[4];
  const float* bqkv = (const float*)d_in[5];
  const float* wo   = (const float*)d_in[6];
  const float* bo   = (const float*)d_in[7];
  const float* ln2g = (const float*)d_in[8];
  const float* ln2b = (const float*)d_in[9];
  const float* w1   = (const float*)d_in[10];
  const float* b1   = (const float*)d_in[11];
  const float* w2   = (const float*)d_in[12];
  const float* b2   = (const float*)d_in[13];
  const float* lnfg = (const float*)d_in[14];
  const float* lnfb = (const float*)d_in[15];

  char* ws = (char*)d_ws;
  size_t off = 0;
  u16*   wqkvT = (u16*)(ws + off);   off += (size_t)NL*TD*DD*2;
  u16*   woT   = (u16*)(ws + off);   off += (size_t)NL*DD*DD*2;
  u16*   w1T   = (u16*)(ws + off);   off += (size_t)NL*DFFN*DD*2;
  u16*   w2T   = (u16*)(ws + off);   off += (size_t)NL*DD*DFFN*2;
  float* h     = (float*)(ws + off); off += (size_t)MM*DD*4;
  u16*   lnb   = (u16*)(ws + off);   off += (size_t)MM*DD*2;
  u16*   Qb    = (u16*)(ws + off);   off += (size_t)BB*HH*SP*64*2;
  u16*   Kb    = (u16*)(ws + off);   off += (size_t)BB*HH*SP*64*2;
  u16*   VTb   = (u16*)(ws + off);   off += (size_t)BB*HH*64*SP*2;
  u16*   attnO = (u16*)(ws + off);   off += (size_t)MM*DD*2;
  u16*   ffh   = (u16*)(ws + off);   off += (size_t)MM*DFFN*2;
  float* P0    = (float*)(ws + off); off += (size_t)MM*DD*4;
  float* P1    = (float*)(ws + off); off += (size_t)MM*DD*4;

  const dim3 tb(32, 8);
  transpose_cast<<<dim3(TD/32,   DD/32,   NL), tb, 0, stream>>>(wqkv, wqkvT, DD,   TD);
  transpose_cast<<<dim3(DD/32,   DD/32,   NL), tb, 0, stream>>>(wo,   woT,   DD,   DD);
  transpose_cast<<<dim3(DFFN/32, DD/32,   NL), tb, 0, stream>>>(w1,   w1T,   DD,   DFFN);
  transpose_cast<<<dim3(DD/32,   DFFN/32, NL), tb, 0, stream>>>(w2,   w2T,   DFFN, DD);
  hipMemcpyAsync(h, x, (size_t)MM*DD*4, hipMemcpyDeviceToDevice, stream);
  hipMemsetAsync(Qb, 0, (size_t)3*BB*HH*SP*64*2, stream);   // zero Q/K/VT arena (pads)

  for (int l = 0; l < NL; ++l) {
    if (l == 0)
      ln_kernel<<<MM, 256, 0, stream>>>(h, ln1g, ln1b, lnb);
    else
      ln_comb<0><<<MM, 256, 0, stream>>>(P0, P1, h, ln1g + (size_t)l*DD, ln1b + (size_t)l*DD,
                                         lnb, nullptr);
    gemm_bt<3><<<dim3(MM/128, TD/128), 256, 0, stream>>>(
        lnb, wqkvT + (size_t)l*TD*DD, bqkv + (size_t)l*TD, nullptr, nullptr, nullptr,
        Qb, Kb, VTb, TD, DD);
    attn_staged<<<dim3(1024 + NTAIL), 256, 0, stream>>>(Qb, Kb, VTb, attnO, npt);
    gemm64<<<dim3(MM/64, DD/128), 256, 0, stream>>>(
        attnO, woT + (size_t)l*DD*DD, bo + (size_t)l*DD, h, h, DD, DD);
    ln_kernel<<<MM, 256, 0, stream>>>(h, ln2g + (size_t)l*DD, ln2b + (size_t)l*DD, lnb);
    gemm_bt<1><<<dim3(MM/128, DFFN/128), 256, 0, stream>>>(
        lnb, w1T + (size_t)l*DFFN*DD, b1 + (size_t)l*DFFN, nullptr, nullptr, ffh,
        nullptr, nullptr, nullptr, DFFN, DD);
    gemm_ffn2<<<dim3(MM/128, DD/128, 2), 256, 0, stream>>>(
        ffh, w2T + (size_t)l*DD*DFFN, b2 + (size_t)l*DD, h, P0, P1, DD, DFFN);
  }
  ln_comb<1><<<MM, 256, 0, stream>>>(P0, P1, h, lnfg, lnfb, nullptr, (float*)d_out);
}